// Round 1
// baseline (9348.242 us; speedup 1.0000x reference)
//
#include <hip/hip_runtime.h>
#include <math.h>

// Autoregressive flow: B independent GRU(2->64) rollouts of T=12 steps,
// each step followed by a tiny MLP head (64->32->4) producing
// dloc (2) and softplus scale (2); y_t = y_{t-1} + dloc + scale * x_t.
//
// Round 1: FP32 thread-per-batch-element baseline. Weights are wave-uniform
// -> scalar loads; h/h_new live in VGPRs; 4-way accumulator dots.

__device__ __forceinline__ float dot64(const float* __restrict__ w, const float (&h)[64]) {
    float a0 = 0.f, a1 = 0.f, a2 = 0.f, a3 = 0.f;
#pragma unroll
    for (int k = 0; k < 64; k += 4) {
        a0 = fmaf(w[k + 0], h[k + 0], a0);
        a1 = fmaf(w[k + 1], h[k + 1], a1);
        a2 = fmaf(w[k + 2], h[k + 2], a2);
        a3 = fmaf(w[k + 3], h[k + 3], a3);
    }
    return (a0 + a1) + (a2 + a3);
}

__device__ __forceinline__ float sigmoid_fast(float v) {
    return 1.f / (1.f + __expf(-v));
}

__device__ __forceinline__ float tanh_fast(float v) {
    // stable for |v| large: exp(2v) -> inf gives 1, -> 0 gives -1
    return 1.f - 2.f / (__expf(2.f * v) + 1.f);
}

__device__ __forceinline__ float softplus_stable(float v) {
    return fmaxf(v, 0.f) + log1pf(__expf(-fabsf(v)));
}

__global__ __launch_bounds__(256)
void arflow_kernel(const float* __restrict__ y_tm1,
                   const float* __restrict__ z,
                   const float* __restrict__ x,
                   const float* __restrict__ Wih,
                   const float* __restrict__ Whh,
                   const float* __restrict__ bih,
                   const float* __restrict__ bhh,
                   const float* __restrict__ W1,
                   const float* __restrict__ b1,
                   const float* __restrict__ W2,
                   const float* __restrict__ b2,
                   float* __restrict__ out,
                   int B, int T)
{
    const int b = blockIdx.x * blockDim.x + threadIdx.x;
    if (b >= B) return;

    float h[64];
    {
        const float4* zp = reinterpret_cast<const float4*>(z + (size_t)b * 64);
#pragma unroll
        for (int i = 0; i < 16; ++i) {
            float4 v = zp[i];
            h[4 * i + 0] = v.x; h[4 * i + 1] = v.y;
            h[4 * i + 2] = v.z; h[4 * i + 3] = v.w;
        }
    }

    float2 y = reinterpret_cast<const float2*>(y_tm1)[b];

    const float2* xrow = reinterpret_cast<const float2*>(x + (size_t)b * T * 2);
    float2* orow = reinterpret_cast<float2*>(out + (size_t)b * T * 2);

    for (int t = 0; t < T; ++t) {
        // ---- GRU cell: h = GRU(y_prev, h) ----
        float hn[64];
#pragma unroll 2
        for (int j = 0; j < 64; ++j) {
            const int jr = j, jz = 64 + j, jn = 128 + j;
            float gr = dot64(Whh + (size_t)jr * 64, h) + bhh[jr]
                     + fmaf(Wih[2 * jr + 0], y.x, fmaf(Wih[2 * jr + 1], y.y, bih[jr]));
            float gz = dot64(Whh + (size_t)jz * 64, h) + bhh[jz]
                     + fmaf(Wih[2 * jz + 0], y.x, fmaf(Wih[2 * jz + 1], y.y, bih[jz]));
            float ghn = dot64(Whh + (size_t)jn * 64, h) + bhh[jn];
            float gin = fmaf(Wih[2 * jn + 0], y.x, fmaf(Wih[2 * jn + 1], y.y, bih[jn]));

            float r = sigmoid_fast(gr);
            float u = sigmoid_fast(gz);
            float n = tanh_fast(gin + r * ghn);
            hn[j] = (1.f - u) * n + u * h[j];
        }
#pragma unroll
        for (int j = 0; j < 64; ++j) h[j] = hn[j];

        // ---- MLP head: dls = relu(h@W1.T + b1) @ W2.T + b2 ----
        float d0 = b2[0], d1 = b2[1], d2 = b2[2], d3 = b2[3];
#pragma unroll 4
        for (int i = 0; i < 32; ++i) {
            float ai = dot64(W1 + (size_t)i * 64, h) + b1[i];
            ai = fmaxf(ai, 0.f);
            d0 = fmaf(W2[0 * 32 + i], ai, d0);
            d1 = fmaf(W2[1 * 32 + i], ai, d1);
            d2 = fmaf(W2[2 * 32 + i], ai, d2);
            d3 = fmaf(W2[3 * 32 + i], ai, d3);
        }

        // ---- flow update ----
        float2 xt = xrow[t];
        float s0 = softplus_stable(d2) + 1e-6f;
        float s1 = softplus_stable(d3) + 1e-6f;
        y.x = y.x + d0 + s0 * xt.x;
        y.y = y.y + d1 + s1 * xt.y;
        orow[t] = y;
    }
}

extern "C" void kernel_launch(void* const* d_in, const int* in_sizes, int n_in,
                              void* d_out, int out_size, void* d_ws, size_t ws_size,
                              hipStream_t stream) {
    const float* y_tm1 = (const float*)d_in[0];
    const float* z     = (const float*)d_in[1];
    const float* x     = (const float*)d_in[2];
    const float* Wih   = (const float*)d_in[3];
    const float* Whh   = (const float*)d_in[4];
    const float* bih   = (const float*)d_in[5];
    const float* bhh   = (const float*)d_in[6];
    const float* W1    = (const float*)d_in[7];
    const float* b1    = (const float*)d_in[8];
    const float* W2    = (const float*)d_in[9];
    const float* b2    = (const float*)d_in[10];
    float* out = (float*)d_out;

    const int B = in_sizes[0] / 2;           // y_tm1 is (B, 2)
    const int T = in_sizes[2] / in_sizes[0]; // x is (B, T, 2) = B*T*2 elems

    dim3 block(256);
    dim3 grid((B + 255) / 256);
    hipLaunchKernelGGL(arflow_kernel, grid, block, 0, stream,
                       y_tm1, z, x, Wih, Whh, bih, bhh, W1, b1, W2, b2, out, B, T);
}

// Round 2
// 1852.910 us; speedup vs baseline: 5.0452x; 5.0452x over previous
//
#include <hip/hip_runtime.h>
#include <math.h>
#include <stdint.h>

// Autoregressive flow via MFMA (bf16), transposed formulation:
//   D[j][batch] = Wtilde[j][:] . htilde[batch][:]
// htilde = [h(64), y.x, y.y, 1, pad0 -> K=96]
// Wtilde rows (256): [0..63]  r-gate   [Whh_r | Wih_r | bih_r+bhh_r]
//                    [64..127] z-gate  [Whh_z | Wih_z | bih_z+bhh_z]
//                    [128..191] h_n    [Whh_n | 0 0   | bhh_n      ]
//                    [192..255] i_n    [  0   | Wih_n | bih_n      ]  (only k-slice 2 nonzero)
// GRU: r=sig(Dr) u=sig(Dz) n=tanh(Di + r*Dn) h'=(1-u)*n + u*h   (u*h path in fp32 regs)
// MLP: a = relu(W1 . h' + b1) via MFMA (K=64, b1 in acc init); dls = a.W2^T + b2 on VALU.

typedef short bf16x8 __attribute__((ext_vector_type(8)));
typedef short bf16x4 __attribute__((ext_vector_type(4)));
typedef float f32x4  __attribute__((ext_vector_type(4)));

#define LDW 104           // padded LDS row stride in bf16 elems (208 B: bank-friendly, 16B aligned)
#define WG_ELEMS (256 * LDW)
#define W1_ELEMS (32 * LDW)

__device__ __forceinline__ short f2bf(float f) {
    union { float f; uint32_t u; } v; v.f = f;
    uint32_t r = v.u + 0x7fffu + ((v.u >> 16) & 1u);
    return (short)(r >> 16);
}

__device__ __forceinline__ float sigf(float x) {
    return __builtin_amdgcn_rcpf(1.f + __expf(-x));
}
__device__ __forceinline__ float tanhf1(float x) {
    return 1.f - 2.f * __builtin_amdgcn_rcpf(__expf(2.f * x) + 1.f);
}
__device__ __forceinline__ float softplusf(float x) {
    return fmaxf(x, 0.f) + log1pf(__expf(-fabsf(x)));
}

// ---------------- weight prep: fp32 globals -> bf16 Wtilde/W1tilde in workspace ----------------
__global__ void prep_kernel(const float* __restrict__ Wih, const float* __restrict__ Whh,
                            const float* __restrict__ bih, const float* __restrict__ bhh,
                            const float* __restrict__ W1,
                            short* __restrict__ wsw) {
    int idx = blockIdx.x * blockDim.x + threadIdx.x;
    const int total = WG_ELEMS + W1_ELEMS;
    if (idx >= total) return;
    float v = 0.f;
    if (idx < WG_ELEMS) {
        int r = idx / LDW, c = idx % LDW;
        int blk = r >> 6, j = r & 63;
        if (blk <= 1) {                 // r-gate / z-gate, combined
            int row = blk * 64 + j;
            if (c < 64) v = Whh[row * 64 + c];
            else if (c == 64) v = Wih[row * 2 + 0];
            else if (c == 65) v = Wih[row * 2 + 1];
            else if (c == 66) v = bih[row] + bhh[row];
        } else if (blk == 2) {          // h_n
            int row = 128 + j;
            if (c < 64) v = Whh[row * 64 + c];
            else if (c == 66) v = bhh[row];
        } else {                        // i_n
            int row = 128 + j;
            if (c == 64) v = Wih[row * 2 + 0];
            else if (c == 65) v = Wih[row * 2 + 1];
            else if (c == 66) v = bih[row];
        }
    } else {
        int k = idx - WG_ELEMS;
        int r = k / LDW, c = k % LDW;
        v = (c < 64) ? W1[r * 64 + c] : 0.f;
    }
    wsw[idx] = f2bf(v);
}

// ---------------- main kernel: 8 waves/block, 32 batch rows/wave ----------------
__global__ __launch_bounds__(512, 2)
void arflow_mfma(const float* __restrict__ y_tm1,
                 const float* __restrict__ z,
                 const float* __restrict__ x,
                 const float* __restrict__ W2,
                 const float* __restrict__ b1,
                 const float* __restrict__ b2,
                 const short* __restrict__ wsw,
                 float* __restrict__ out,
                 int B, int T)
{
    __shared__ __align__(16) short Wl[WG_ELEMS];      // 53248 B
    __shared__ __align__(16) short W1l[W1_ELEMS];     //  6656 B
    __shared__ __align__(16) short Hl[8][32 * LDW];   // 53248 B (per-wave htilde, 32 rows x 104)

    const int tid  = threadIdx.x;
    const int wave = tid >> 6;
    const int lane = tid & 63;
    const int g    = lane >> 4;   // k-group / reduce group
    const int ln   = lane & 15;   // batch-within-tile / A-row

    // ---- stage weights global->LDS (one time) ----
    {
        const uint4* wsv = reinterpret_cast<const uint4*>(wsw);
        uint4* wl  = reinterpret_cast<uint4*>(Wl);
        uint4* w1l = reinterpret_cast<uint4*>(W1l);
        for (int i = tid; i < WG_ELEMS / 8; i += 512) wl[i] = wsv[i];
        for (int i = tid; i < W1_ELEMS / 8; i += 512) w1l[i] = wsv[WG_ELEMS / 8 + i];
    }

    const int base = blockIdx.x * 256 + wave * 32;
    short* hl = &Hl[wave][0];

    // ---- init htilde: zero pad cols 64..95, load z (bf16), y slots, fp32 h in regs ----
    {
        uint4 z4 = make_uint4(0, 0, 0, 0);
        *reinterpret_cast<uint4*>(&hl[ln * LDW + 64 + g * 8]) = z4;
        *reinterpret_cast<uint4*>(&hl[(ln + 16) * LDW + 64 + g * 8]) = z4;
    }

    float hpr[4][2][4];   // fp32 h state, D-layout: [mg][n][q] = h[batch n*16+ln][16mg+4g+q]
    float2 y[2];

#pragma unroll
    for (int n = 0; n < 2; ++n) {
        int gr = base + n * 16 + ln;
        bool ok = gr < B;
        // z -> LDS bf16 (this lane covers cols g*16 .. g*16+15 of its two rows)
#pragma unroll
        for (int cc = 0; cc < 4; ++cc) {
            int c0 = g * 16 + cc * 4;
            float4 zv = ok ? reinterpret_cast<const float4*>(z)[(size_t)gr * 16 + (c0 >> 2)]
                           : make_float4(0.f, 0.f, 0.f, 0.f);
            bf16x4 pk; pk[0] = f2bf(zv.x); pk[1] = f2bf(zv.y); pk[2] = f2bf(zv.z); pk[3] = f2bf(zv.w);
            *reinterpret_cast<bf16x4*>(&hl[(n * 16 + ln) * LDW + c0]) = pk;
        }
        // fp32 h regs (D-layout cols differ from the LDS cols this lane wrote)
#pragma unroll
        for (int mg = 0; mg < 4; ++mg) {
            float4 zv = ok ? reinterpret_cast<const float4*>(z)[(size_t)gr * 16 + ((mg * 16 + g * 4) >> 2)]
                           : make_float4(0.f, 0.f, 0.f, 0.f);
            hpr[mg][n][0] = zv.x; hpr[mg][n][1] = zv.y; hpr[mg][n][2] = zv.z; hpr[mg][n][3] = zv.w;
        }
        float2 yv = ok ? reinterpret_cast<const float2*>(y_tm1)[gr] : make_float2(0.f, 0.f);
        y[n] = yv;
    }
    if (g < 2) {  // one writer per row: y slot + constant 1
        int n = g;
        bf16x4 pk; pk[0] = f2bf(y[n].x); pk[1] = f2bf(y[n].y); pk[2] = f2bf(1.f); pk[3] = 0;
        *reinterpret_cast<bf16x4*>(&hl[(n * 16 + ln) * LDW + 64]) = pk;
    }

    // ---- preload W2 (fp32), b1, b2 into regs ----
    float w2v[4][8];   // [c][mt*4+q], i = 16*mt + 4*g + q
#pragma unroll
    for (int c = 0; c < 4; ++c)
#pragma unroll
        for (int mt = 0; mt < 2; ++mt) {
            float4 t = reinterpret_cast<const float4*>(W2)[(c * 32 + mt * 16 + g * 4) >> 2];
            w2v[c][mt * 4 + 0] = t.x; w2v[c][mt * 4 + 1] = t.y;
            w2v[c][mt * 4 + 2] = t.z; w2v[c][mt * 4 + 3] = t.w;
        }
    float b1v[8];
#pragma unroll
    for (int mt = 0; mt < 2; ++mt) {
        float4 t = reinterpret_cast<const float4*>(b1)[(mt * 16 + g * 4) >> 2];
        b1v[mt * 4 + 0] = t.x; b1v[mt * 4 + 1] = t.y; b1v[mt * 4 + 2] = t.z; b1v[mt * 4 + 3] = t.w;
    }
    float b2v[4] = { b2[0], b2[1], b2[2], b2[3] };

    __syncthreads();   // weights staged; per-wave Hl needs no cross-wave sync

    for (int t = 0; t < T; ++t) {
        // B-fragments: htilde for both n-tiles, 3 k-slices
        bf16x8 bf[2][3];
#pragma unroll
        for (int n = 0; n < 2; ++n)
#pragma unroll
            for (int ks = 0; ks < 3; ++ks)
                bf[n][ks] = *reinterpret_cast<const bf16x8*>(&hl[(n * 16 + ln) * LDW + ks * 32 + g * 8]);

        // ---- GRU: 4 j-tile groups ----
#pragma unroll
        for (int mg = 0; mg < 4; ++mg) {
            f32x4 aR[2] = { {0,0,0,0}, {0,0,0,0} };
            f32x4 aZ[2] = { {0,0,0,0}, {0,0,0,0} };
            f32x4 aN[2] = { {0,0,0,0}, {0,0,0,0} };
            f32x4 aI[2] = { {0,0,0,0}, {0,0,0,0} };
#pragma unroll
            for (int ks = 0; ks < 3; ++ks) {
                bf16x8 wR = *reinterpret_cast<const bf16x8*>(&Wl[(       mg * 16 + ln) * LDW + ks * 32 + g * 8]);
                bf16x8 wZ = *reinterpret_cast<const bf16x8*>(&Wl[( 64 +  mg * 16 + ln) * LDW + ks * 32 + g * 8]);
                bf16x8 wN = *reinterpret_cast<const bf16x8*>(&Wl[(128 +  mg * 16 + ln) * LDW + ks * 32 + g * 8]);
#pragma unroll
                for (int n = 0; n < 2; ++n) {
                    aR[n] = __builtin_amdgcn_mfma_f32_16x16x32_bf16(wR, bf[n][ks], aR[n], 0, 0, 0);
                    aZ[n] = __builtin_amdgcn_mfma_f32_16x16x32_bf16(wZ, bf[n][ks], aZ[n], 0, 0, 0);
                    aN[n] = __builtin_amdgcn_mfma_f32_16x16x32_bf16(wN, bf[n][ks], aN[n], 0, 0, 0);
                }
            }
            {   // i_n: only k-slice 2 nonzero
                bf16x8 wI = *reinterpret_cast<const bf16x8*>(&Wl[(192 + mg * 16 + ln) * LDW + 64 + g * 8]);
#pragma unroll
                for (int n = 0; n < 2; ++n)
                    aI[n] = __builtin_amdgcn_mfma_f32_16x16x32_bf16(wI, bf[n][2], aI[n], 0, 0, 0);
            }
            // gates + h update (fp32 memory path), write h' bf16 to LDS
#pragma unroll
            for (int n = 0; n < 2; ++n) {
                bf16x4 hnw;
#pragma unroll
                for (int q = 0; q < 4; ++q) {
                    float r  = sigf(aR[n][q]);
                    float u  = sigf(aZ[n][q]);
                    float nn = tanhf1(aI[n][q] + r * aN[n][q]);
                    float hq = (1.f - u) * nn + u * hpr[mg][n][q];
                    hpr[mg][n][q] = hq;
                    hnw[q] = f2bf(hq);
                }
                *reinterpret_cast<bf16x4*>(&hl[(n * 16 + ln) * LDW + mg * 16 + g * 4]) = hnw;
            }
        }

        // ---- MLP layer 1 via MFMA (K=64, b1 folded into acc init) ----
        f32x4 aM[2][2];
#pragma unroll
        for (int mt = 0; mt < 2; ++mt)
#pragma unroll
            for (int n = 0; n < 2; ++n) {
                aM[mt][n][0] = b1v[mt * 4 + 0]; aM[mt][n][1] = b1v[mt * 4 + 1];
                aM[mt][n][2] = b1v[mt * 4 + 2]; aM[mt][n][3] = b1v[mt * 4 + 3];
            }
        bf16x8 mb[2][2];
#pragma unroll
        for (int n = 0; n < 2; ++n)
#pragma unroll
            for (int ks = 0; ks < 2; ++ks)
                mb[n][ks] = *reinterpret_cast<const bf16x8*>(&hl[(n * 16 + ln) * LDW + ks * 32 + g * 8]);
#pragma unroll
        for (int mt = 0; mt < 2; ++mt)
#pragma unroll
            for (int ks = 0; ks < 2; ++ks) {
                bf16x8 wM = *reinterpret_cast<const bf16x8*>(&W1l[(mt * 16 + ln) * LDW + ks * 32 + g * 8]);
#pragma unroll
                for (int n = 0; n < 2; ++n)
                    aM[mt][n] = __builtin_amdgcn_mfma_f32_16x16x32_bf16(wM, mb[n][ks], aM[mt][n], 0, 0, 0);
            }

        // ---- MLP layer 2 on VALU (fp32) + cross-g reduce ----
        float d[2][4];
#pragma unroll
        for (int n = 0; n < 2; ++n) {
            float am[8];
#pragma unroll
            for (int mt = 0; mt < 2; ++mt)
#pragma unroll
                for (int q = 0; q < 4; ++q)
                    am[mt * 4 + q] = fmaxf(aM[mt][n][q], 0.f);
#pragma unroll
            for (int c = 0; c < 4; ++c) {
                float s = 0.f;
#pragma unroll
                for (int i = 0; i < 8; ++i) s = fmaf(am[i], w2v[c][i], s);
                s += __shfl_xor(s, 16);
                s += __shfl_xor(s, 32);
                d[n][c] = s + b2v[c];
            }
        }

        // ---- flow update, store y, refresh y slot in LDS ----
#pragma unroll
        for (int n = 0; n < 2; ++n) {
            int gr = base + n * 16 + ln;
            bool ok = gr < B;
            float2 xt = ok ? reinterpret_cast<const float2*>(x)[(size_t)gr * T + t]
                           : make_float2(0.f, 0.f);
            float s0 = softplusf(d[n][2]) + 1e-6f;
            float s1 = softplusf(d[n][3]) + 1e-6f;
            y[n].x += d[n][0] + s0 * xt.x;
            y[n].y += d[n][1] + s1 * xt.y;
            if (g == 0 && ok)
                reinterpret_cast<float2*>(out)[(size_t)gr * T + t] = y[n];
        }
        if (g < 2) {
            int n = g;
            uint32_t pk = (uint32_t)(uint16_t)f2bf(y[n].x) | ((uint32_t)(uint16_t)f2bf(y[n].y) << 16);
            *reinterpret_cast<uint32_t*>(&hl[(n * 16 + ln) * LDW + 64]) = pk;
        }
    }
}

extern "C" void kernel_launch(void* const* d_in, const int* in_sizes, int n_in,
                              void* d_out, int out_size, void* d_ws, size_t ws_size,
                              hipStream_t stream) {
    const float* y_tm1 = (const float*)d_in[0];
    const float* z     = (const float*)d_in[1];
    const float* x     = (const float*)d_in[2];
    const float* Wih   = (const float*)d_in[3];
    const float* Whh   = (const float*)d_in[4];
    const float* bih   = (const float*)d_in[5];
    const float* bhh   = (const float*)d_in[6];
    const float* W1    = (const float*)d_in[7];
    const float* b1    = (const float*)d_in[8];
    const float* W2    = (const float*)d_in[9];
    const float* b2    = (const float*)d_in[10];
    float* out = (float*)d_out;
    short* wsw = (short*)d_ws;

    const int B = in_sizes[0] / 2;
    const int T = in_sizes[2] / in_sizes[0];

    const int prep_total = WG_ELEMS + W1_ELEMS;
    hipLaunchKernelGGL(prep_kernel, dim3((prep_total + 255) / 256), dim3(256), 0, stream,
                       Wih, Whh, bih, bhh, W1, wsw);

    const int nblk = (B + 255) / 256;
    hipLaunchKernelGGL(arflow_mfma, dim3(nblk), dim3(512), 0, stream,
                       y_tm1, z, x, W2, b1, b2, wsw, out, B, T);
}

// Round 3
// 1104.094 us; speedup vs baseline: 8.4669x; 1.6782x over previous
//
#include <hip/hip_runtime.h>
#include <math.h>
#include <stdint.h>

// Autoregressive flow via MFMA (bf16):
//   D[j][batch] = W[j][:] . h[batch][:]   (A-frag = weight rows, B-frag = h cols)
// GRU gates via 16x16x32 bf16 MFMA; y/bias enter through a sparse "ks2" slice
// (nonzero only on g==0 lanes: k=64..66 = [y.x, y.y, 1]). h kept fp32 in regs
// (D-layout) for the u*h memory path; bf16 h round-trips through per-wave LDS
// to convert D-layout -> B-frag layout. MLP1 via MFMA (b1 in acc init),
// MLP2 via one padded MFMA (W2 rows 4->16, d lands on g==0 lanes).
// x/y staged in LDS: coalesced load of x up-front, y written into the same
// slots per step, coalesced store at the end.

typedef short bf16x8 __attribute__((ext_vector_type(8)));
typedef short bf16x4 __attribute__((ext_vector_type(4)));
typedef float f32x4  __attribute__((ext_vector_type(4)));

// workspace layout (shorts)
#define OFF_RZN 0          // [192][64]  Whh rows (R,Z,N)
#define OFF_KS2 12288      // [4][64][8] sets R,Z,N,I: (Wih0, Wih1, bias, 0...)
#define OFF_W2F 14336      // [64][8]    per-lane W2 A-frag (rows padded 4->16)
#define OFF_W1P 14848      // [32][72]   W1 padded rows
#define WS_TOT  17152

#define W1LDW 72           // 144 B rows: 9x16B, odd -> conflict-free b128
#define HLW   104          // 208 B rows: 13x16B, odd -> conflict-free b128
#define XYW   28           // 112 B rows: 7x16B, odd -> conflict-free b128

__device__ __forceinline__ short f2bf(float f) {
    union { float f; uint32_t u; } v; v.f = f;
    uint32_t r = v.u + 0x7fffu + ((v.u >> 16) & 1u);
    return (short)(r >> 16);
}
__device__ __forceinline__ float sigf(float x) {
    return __builtin_amdgcn_rcpf(1.f + __expf(-x));
}
__device__ __forceinline__ float tanhf1(float x) {
    return 1.f - 2.f * __builtin_amdgcn_rcpf(__expf(2.f * x) + 1.f);
}
__device__ __forceinline__ float softplusf(float x) {
    return fmaxf(x, 0.f) + log1pf(__expf(-fabsf(x)));
}

// ---------------- weight prep ----------------
__global__ void prep_kernel(const float* __restrict__ Wih, const float* __restrict__ Whh,
                            const float* __restrict__ bih, const float* __restrict__ bhh,
                            const float* __restrict__ W1, const float* __restrict__ W2,
                            short* __restrict__ wsw) {
    int idx = blockIdx.x * blockDim.x + threadIdx.x;
    if (idx >= WS_TOT) return;
    float v = 0.f;
    if (idx < OFF_KS2) {
        v = Whh[idx];                                   // [192][64] direct
    } else if (idx < OFF_W2F) {
        int i = idx - OFF_KS2;
        int s = i >> 9, r = (i >> 3) & 63, j = i & 7;
        if (s == 0) {            // R
            if (j == 0) v = Wih[2 * r];
            else if (j == 1) v = Wih[2 * r + 1];
            else if (j == 2) v = bih[r] + bhh[r];
        } else if (s == 1) {     // Z
            int row = 64 + r;
            if (j == 0) v = Wih[2 * row];
            else if (j == 1) v = Wih[2 * row + 1];
            else if (j == 2) v = bih[row] + bhh[row];
        } else if (s == 2) {     // N (bias bhh_n only; multiplied by r later)
            if (j == 2) v = bhh[128 + r];
        } else {                 // I (i_n = Wih_n.y + bih_n)
            int row = 128 + r;
            if (j == 0) v = Wih[2 * row];
            else if (j == 1) v = Wih[2 * row + 1];
            else if (j == 2) v = bih[row];
        }
    } else if (idx < OFF_W1P) {
        int i = idx - OFF_W2F;
        int l = i >> 3, j = i & 7;
        int lnn = l & 15, gg = l >> 4;
        v = (lnn < 4) ? W2[lnn * 32 + gg * 8 + j] : 0.f;
    } else {
        int i = idx - OFF_W1P;
        int r = i / W1LDW, c = i - r * W1LDW;
        v = (c < 64) ? W1[r * 64 + c] : 0.f;
    }
    wsw[idx] = f2bf(v);
}

// ---------------- main kernel: 4 waves/block, 32 rows/wave ----------------
__global__ __launch_bounds__(256, 2)
void arflow3(const float* __restrict__ y_tm1,
             const float* __restrict__ z,
             const float* __restrict__ x,
             const float* __restrict__ b1,
             const float* __restrict__ b2,
             const short* __restrict__ wsw,
             float* __restrict__ out,
             int B, int T)
{
    __shared__ __align__(16) float XY[128 * XYW];        // 14336 B (x, overwritten by y)
    __shared__ __align__(16) short HL[4][32 * HLW];      // 26624 B (per-wave h + a)
    __shared__ __align__(16) short KS2[4 * 64 * 8 + 8];  //  4112 B (+16B zero chunk)
    __shared__ __align__(16) short W1L[32 * W1LDW];      //  4608 B

    const int tid  = threadIdx.x;
    const int wave = tid >> 6;
    const int lane = tid & 63;
    const int g    = lane >> 4;
    const int ln   = lane & 15;
    const int base = blockIdx.x * 128;
    const int rows = (B - base < 128) ? (B - base) : 128;
    const int NF4  = T >> 1;   // float4s per x-row (T*2/4)

    // ---- stage x -> XY (coalesced) ----
    {
        const float4* xg = reinterpret_cast<const float4*>(x) + (size_t)base * NF4;
        const int tot = 128 * NF4;
        for (int i = tid; i < tot; i += 256) {
            float4 v = (i < rows * NF4) ? xg[i] : make_float4(0.f, 0.f, 0.f, 0.f);
            int r = i / NF4, c = i - r * NF4;
            *reinterpret_cast<float4*>(&XY[r * XYW + c * 4]) = v;
        }
    }
    // ---- stage KS2 + W1L ----
    {
        const uint32_t* src = reinterpret_cast<const uint32_t*>(wsw + OFF_KS2);
        uint32_t* dst = reinterpret_cast<uint32_t*>(KS2);
        for (int i = tid; i < 1024; i += 256) dst[i] = src[i];
        if (tid < 4) dst[1024 + tid] = 0;   // zero chunk at short-offset 2048
        const uint32_t* s1 = reinterpret_cast<const uint32_t*>(wsw + OFF_W1P);
        uint32_t* d1 = reinterpret_cast<uint32_t*>(W1L);
        for (int i = tid; i < (32 * W1LDW) / 2; i += 256) d1[i] = s1[i];
    }

    // ---- loop-invariant weights -> VGPRs ----
    bf16x8 wR[4][2], wZ[4][2], wN[4][2];
#pragma unroll
    for (int mg = 0; mg < 4; ++mg)
#pragma unroll
        for (int ks = 0; ks < 2; ++ks) {
            wR[mg][ks] = *reinterpret_cast<const bf16x8*>(wsw + ((      mg * 16 + ln) * 64 + ks * 32 + g * 8));
            wZ[mg][ks] = *reinterpret_cast<const bf16x8*>(wsw + ((64  + mg * 16 + ln) * 64 + ks * 32 + g * 8));
            wN[mg][ks] = *reinterpret_cast<const bf16x8*>(wsw + ((128 + mg * 16 + ln) * 64 + ks * 32 + g * 8));
        }
    bf16x8 w2f = *reinterpret_cast<const bf16x8*>(wsw + OFF_W2F + lane * 8);

    float b1v[8];
#pragma unroll
    for (int mt = 0; mt < 2; ++mt) {
        float4 tv = reinterpret_cast<const float4*>(b1)[mt * 4 + g];
        b1v[mt * 4 + 0] = tv.x; b1v[mt * 4 + 1] = tv.y;
        b1v[mt * 4 + 2] = tv.z; b1v[mt * 4 + 3] = tv.w;
    }
    f32x4 dInit;
    {
        float4 bb = *reinterpret_cast<const float4*>(b2);
        dInit[0] = (g == 0) ? bb.x : 0.f;
        dInit[1] = (g == 0) ? bb.y : 0.f;
        dInit[2] = (g == 0) ? bb.z : 0.f;
        dInit[3] = (g == 0) ? bb.w : 0.f;
    }

    // ---- init h (from z, fp32 regs in D-layout), y ----
    float hpr[4][2][4];
    float2 y[2];
    short* hl = &HL[wave][0];
#pragma unroll
    for (int n = 0; n < 2; ++n) {
        int gr = base + wave * 32 + n * 16 + ln;
        bool ok = gr < B;
#pragma unroll
        for (int mg = 0; mg < 4; ++mg) {
            float4 zv = ok ? reinterpret_cast<const float4*>(z)[(size_t)gr * 16 + mg * 4 + g]
                           : make_float4(0.f, 0.f, 0.f, 0.f);
            hpr[mg][n][0] = zv.x; hpr[mg][n][1] = zv.y;
            hpr[mg][n][2] = zv.z; hpr[mg][n][3] = zv.w;
        }
        float2 yv = ok ? reinterpret_cast<const float2*>(y_tm1)[gr] : make_float2(0.f, 0.f);
        y[n] = yv;
    }
    // initial h -> hl (bf16, D-layout store), read initial B-frags
#pragma unroll
    for (int n = 0; n < 2; ++n)
#pragma unroll
        for (int mg = 0; mg < 4; ++mg) {
            bf16x4 p;
            p[0] = f2bf(hpr[mg][n][0]); p[1] = f2bf(hpr[mg][n][1]);
            p[2] = f2bf(hpr[mg][n][2]); p[3] = f2bf(hpr[mg][n][3]);
            *reinterpret_cast<bf16x4*>(&hl[(n * 16 + ln) * HLW + mg * 16 + g * 4]) = p;
        }
    bf16x8 hb[2][2];
#pragma unroll
    for (int n = 0; n < 2; ++n)
#pragma unroll
        for (int ks = 0; ks < 2; ++ks)
            hb[n][ks] = *reinterpret_cast<const bf16x8*>(&hl[(n * 16 + ln) * HLW + ks * 32 + g * 8]);

    __syncthreads();

    const short ONEg0 = (g == 0) ? (short)0x3F80 : (short)0;

    for (int t = 0; t < T; ++t) {
        asm volatile("" ::: "memory");   // block LICM of in-loop LDS reads (reg-pressure guard)

        // ks2 B-frags: k=64..66 = [y.x, y.y, 1] on g==0 lanes, else 0
        bf16x8 yb[2];
#pragma unroll
        for (int n = 0; n < 2; ++n) {
            short ax = (g == 0) ? f2bf(y[n].x) : (short)0;
            short ay = (g == 0) ? f2bf(y[n].y) : (short)0;
            bf16x8 v = { ax, ay, ONEg0, 0, 0, 0, 0, 0 };
            yb[n] = v;
        }

        // ---- GRU ----
#pragma unroll
        for (int mg = 0; mg < 4; ++mg) {
            const int ro8 = (mg * 16 + ln) * 8;
            bf16x8 aR2 = *reinterpret_cast<const bf16x8*>(&KS2[(g == 0) ? (0 * 512 + ro8) : 2048]);
            bf16x8 aZ2 = *reinterpret_cast<const bf16x8*>(&KS2[(g == 0) ? (1 * 512 + ro8) : 2048]);
            bf16x8 aN2 = *reinterpret_cast<const bf16x8*>(&KS2[(g == 0) ? (2 * 512 + ro8) : 2048]);
            bf16x8 aI2 = *reinterpret_cast<const bf16x8*>(&KS2[(g == 0) ? (3 * 512 + ro8) : 2048]);
            f32x4 aR[2], aZ[2], aN[2], aI[2];
#pragma unroll
            for (int n = 0; n < 2; ++n) {
                aR[n] = f32x4{0.f, 0.f, 0.f, 0.f}; aZ[n] = f32x4{0.f, 0.f, 0.f, 0.f};
                aN[n] = f32x4{0.f, 0.f, 0.f, 0.f}; aI[n] = f32x4{0.f, 0.f, 0.f, 0.f};
            }
#pragma unroll
            for (int ks = 0; ks < 2; ++ks)
#pragma unroll
                for (int n = 0; n < 2; ++n) {
                    aR[n] = __builtin_amdgcn_mfma_f32_16x16x32_bf16(wR[mg][ks], hb[n][ks], aR[n], 0, 0, 0);
                    aZ[n] = __builtin_amdgcn_mfma_f32_16x16x32_bf16(wZ[mg][ks], hb[n][ks], aZ[n], 0, 0, 0);
                    aN[n] = __builtin_amdgcn_mfma_f32_16x16x32_bf16(wN[mg][ks], hb[n][ks], aN[n], 0, 0, 0);
                }
#pragma unroll
            for (int n = 0; n < 2; ++n) {
                aR[n] = __builtin_amdgcn_mfma_f32_16x16x32_bf16(aR2, yb[n], aR[n], 0, 0, 0);
                aZ[n] = __builtin_amdgcn_mfma_f32_16x16x32_bf16(aZ2, yb[n], aZ[n], 0, 0, 0);
                aN[n] = __builtin_amdgcn_mfma_f32_16x16x32_bf16(aN2, yb[n], aN[n], 0, 0, 0);
                aI[n] = __builtin_amdgcn_mfma_f32_16x16x32_bf16(aI2, yb[n], aI[n], 0, 0, 0);
            }
#pragma unroll
            for (int n = 0; n < 2; ++n) {
                bf16x4 p;
#pragma unroll
                for (int q = 0; q < 4; ++q) {
                    float r  = sigf(aR[n][q]);
                    float u  = sigf(aZ[n][q]);
                    float nn = tanhf1(fmaf(r, aN[n][q], aI[n][q]));
                    float hq = fmaf(u, hpr[mg][n][q] - nn, nn);   // (1-u)*n + u*h
                    hpr[mg][n][q] = hq;
                    p[q] = f2bf(hq);
                }
                *reinterpret_cast<bf16x4*>(&hl[(n * 16 + ln) * HLW + mg * 16 + g * 4]) = p;
            }
        }

        // ---- re-read h' B-frags (used by MLP1 now and GRU next step) ----
#pragma unroll
        for (int n = 0; n < 2; ++n)
#pragma unroll
            for (int ks = 0; ks < 2; ++ks)
                hb[n][ks] = *reinterpret_cast<const bf16x8*>(&hl[(n * 16 + ln) * HLW + ks * 32 + g * 8]);

        // ---- MLP1 via MFMA (b1 in acc init) ----
        f32x4 aM[2][2];
#pragma unroll
        for (int mt = 0; mt < 2; ++mt)
#pragma unroll
            for (int n = 0; n < 2; ++n) {
                aM[mt][n][0] = b1v[mt * 4 + 0]; aM[mt][n][1] = b1v[mt * 4 + 1];
                aM[mt][n][2] = b1v[mt * 4 + 2]; aM[mt][n][3] = b1v[mt * 4 + 3];
            }
#pragma unroll
        for (int mt = 0; mt < 2; ++mt)
#pragma unroll
            for (int ks = 0; ks < 2; ++ks) {
                bf16x8 wM = *reinterpret_cast<const bf16x8*>(&W1L[(mt * 16 + ln) * W1LDW + ks * 32 + g * 8]);
#pragma unroll
                for (int n = 0; n < 2; ++n)
                    aM[mt][n] = __builtin_amdgcn_mfma_f32_16x16x32_bf16(wM, hb[n][ks], aM[mt][n], 0, 0, 0);
            }

        // ---- relu(a) -> hl cols 64..95, MLP2 via padded MFMA ----
#pragma unroll
        for (int n = 0; n < 2; ++n)
#pragma unroll
            for (int mt = 0; mt < 2; ++mt) {
                bf16x4 p;
#pragma unroll
                for (int q = 0; q < 4; ++q) p[q] = f2bf(fmaxf(aM[mt][n][q], 0.f));
                *reinterpret_cast<bf16x4*>(&hl[(n * 16 + ln) * HLW + 64 + mt * 16 + g * 4]) = p;
            }
        f32x4 aD[2];
#pragma unroll
        for (int n = 0; n < 2; ++n) {
            bf16x8 ab = *reinterpret_cast<const bf16x8*>(&hl[(n * 16 + ln) * HLW + 64 + g * 8]);
            aD[n] = __builtin_amdgcn_mfma_f32_16x16x32_bf16(w2f, ab, dInit, 0, 0, 0);
        }

        // ---- flow update (d valid on g==0 lanes; aD==0 on g>0 so y stays finite) ----
#pragma unroll
        for (int n = 0; n < 2; ++n) {
            int rl = wave * 32 + n * 16 + ln;
            float2 xt = *reinterpret_cast<const float2*>(&XY[rl * XYW + t * 2]);
            float s0 = softplusf(aD[n][2]) + 1e-6f;
            float s1 = softplusf(aD[n][3]) + 1e-6f;
            y[n].x += aD[n][0] + s0 * xt.x;
            y[n].y += aD[n][1] + s1 * xt.y;
            if (g == 0)
                *reinterpret_cast<float2*>(&XY[rl * XYW + t * 2]) = y[n];
        }
    }

    __syncthreads();
    // ---- coalesced store XY -> out ----
    {
        float4* og = reinterpret_cast<float4*>(out) + (size_t)base * NF4;
        const int tot = 128 * NF4;
        for (int i = tid; i < tot; i += 256) {
            if (i < rows * NF4) {
                int r = i / NF4, c = i - r * NF4;
                og[i] = *reinterpret_cast<const float4*>(&XY[r * XYW + c * 4]);
            }
        }
    }
}

extern "C" void kernel_launch(void* const* d_in, const int* in_sizes, int n_in,
                              void* d_out, int out_size, void* d_ws, size_t ws_size,
                              hipStream_t stream) {
    const float* y_tm1 = (const float*)d_in[0];
    const float* z     = (const float*)d_in[1];
    const float* x     = (const float*)d_in[2];
    const float* Wih   = (const float*)d_in[3];
    const float* Whh   = (const float*)d_in[4];
    const float* bih   = (const float*)d_in[5];
    const float* bhh   = (const float*)d_in[6];
    const float* W1    = (const float*)d_in[7];
    const float* b1    = (const float*)d_in[8];
    const float* W2    = (const float*)d_in[9];
    const float* b2    = (const float*)d_in[10];
    float* out = (float*)d_out;
    short* wsw = (short*)d_ws;

    const int B = in_sizes[0] / 2;
    const int T = in_sizes[2] / in_sizes[0];

    hipLaunchKernelGGL(prep_kernel, dim3((WS_TOT + 255) / 256), dim3(256), 0, stream,
                       Wih, Whh, bih, bhh, W1, W2, wsw);

    const int nblk = (B + 127) / 128;
    hipLaunchKernelGGL(arflow3, dim3(nblk), dim3(256), 0, stream,
                       y_tm1, z, x, b1, b2, wsw, out, B, T);
}

// Round 4
// 908.261 us; speedup vs baseline: 10.2925x; 1.2156x over previous
//
#include <hip/hip_runtime.h>
#include <math.h>
#include <stdint.h>

// Autoregressive flow via MFMA (bf16):
//   D[j][batch] = W[j][:] . h[batch][:]   (A-frag = weight rows, B-frag = h cols)
// GRU gates via 16x16x32 bf16 MFMA; y/bias enter through a sparse "ks2" slice
// (B-rows k=0..2 = [y.x, y.y, 1], nonzero only on g==0 lanes -> A-frag on g>0
// lanes is don't-care => uniform broadcast addressing, no masks).
// h kept fp32 in regs (D-layout) for the u*h memory path; bf16 h round-trips
// through per-wave LDS to convert D-layout -> B-frag layout. MLP1 via MFMA
// (b1 as C-operand), MLP2 via one padded MFMA (W2 rows 4->16, d on g==0).
// x/y staged in LDS: coalesced load of x up-front, y written into the same
// slots per step, coalesced store at the end.

typedef short bf16x8 __attribute__((ext_vector_type(8)));
typedef float f32x4  __attribute__((ext_vector_type(4)));

// workspace layout (shorts)
#define OFF_RZN 0          // [192][64]  Whh rows (R,Z,N)
#define OFF_KS2 12288      // [4][64][8] sets R,Z,N,I: (Wih0, Wih1, bias, 0...)
#define OFF_W2F 14336      // [64][8]    per-lane W2 A-frag (rows padded 4->16)
#define OFF_W1P 14848      // [32][72]   W1 padded rows
#define WS_TOT  17152

#define W1LDW 72           // 144 B rows: 9x16B -> conflict-friendly b128
#define HLW   104          // 208 B rows: 13x16B
#define XYW   28           // 112 B rows: 7x16B

__device__ __forceinline__ short f2bf(float f) {
    union { float f; uint32_t u; } v; v.f = f;
    uint32_t r = v.u + 0x7fffu + ((v.u >> 16) & 1u);
    return (short)(r >> 16);
}
__device__ __forceinline__ uint32_t cvtpk(float lo, float hi) {
    uint32_t r;
    asm("v_cvt_pk_bf16_f32 %0, %1, %2" : "=v"(r) : "v"(lo), "v"(hi));
    return r;
}
__device__ __forceinline__ float sigf(float x) {
    return __builtin_amdgcn_rcpf(1.f + __expf(-x));
}
__device__ __forceinline__ float tanhf1(float x) {
    return 1.f - 2.f * __builtin_amdgcn_rcpf(__expf(2.f * x) + 1.f);
}
__device__ __forceinline__ float softplusf(float x) {
    // max(x,0) + log(1+exp(-|x|)) with fast log/exp (no log1pf lib expansion)
    return fmaxf(x, 0.f) + __logf(1.f + __expf(-fabsf(x)));
}

// ---------------- weight prep ----------------
__global__ void prep_kernel(const float* __restrict__ Wih, const float* __restrict__ Whh,
                            const float* __restrict__ bih, const float* __restrict__ bhh,
                            const float* __restrict__ W1, const float* __restrict__ W2,
                            short* __restrict__ wsw) {
    int idx = blockIdx.x * blockDim.x + threadIdx.x;
    if (idx >= WS_TOT) return;
    float v = 0.f;
    if (idx < OFF_KS2) {
        v = Whh[idx];                                   // [192][64] direct
    } else if (idx < OFF_W2F) {
        int i = idx - OFF_KS2;
        int s = i >> 9, r = (i >> 3) & 63, j = i & 7;
        if (s == 0) {            // R
            if (j == 0) v = Wih[2 * r];
            else if (j == 1) v = Wih[2 * r + 1];
            else if (j == 2) v = bih[r] + bhh[r];
        } else if (s == 1) {     // Z
            int row = 64 + r;
            if (j == 0) v = Wih[2 * row];
            else if (j == 1) v = Wih[2 * row + 1];
            else if (j == 2) v = bih[row] + bhh[row];
        } else if (s == 2) {     // N (bias bhh_n only; multiplied by r later)
            if (j == 2) v = bhh[128 + r];
        } else {                 // I (i_n = Wih_n.y + bih_n)
            int row = 128 + r;
            if (j == 0) v = Wih[2 * row];
            else if (j == 1) v = Wih[2 * row + 1];
            else if (j == 2) v = bih[row];
        }
    } else if (idx < OFF_W1P) {
        int i = idx - OFF_W2F;
        int l = i >> 3, j = i & 7;
        int lnn = l & 15, gg = l >> 4;
        v = (lnn < 4) ? W2[lnn * 32 + gg * 8 + j] : 0.f;
    } else {
        int i = idx - OFF_W1P;
        int r = i / W1LDW, c = i - r * W1LDW;
        v = (c < 64) ? W1[r * 64 + c] : 0.f;
    }
    wsw[idx] = f2bf(v);
}

// ---------------- main kernel: 4 waves/block, 32 rows/wave ----------------
__global__ __launch_bounds__(256, 2)
void arflow4(const float* __restrict__ y_tm1,
             const float* __restrict__ z,
             const float* __restrict__ x,
             const float* __restrict__ b1,
             const float* __restrict__ b2,
             const short* __restrict__ wsw,
             float* __restrict__ out,
             int B, int T)
{
    __shared__ __align__(16) float XY[128 * XYW];        // 14336 B (x, overwritten by y)
    __shared__ __align__(16) short HL[4][32 * HLW];      // 26624 B (per-wave h + a)
    __shared__ __align__(16) short KS2[4 * 64 * 8];      //  8192 B
    __shared__ __align__(16) short W1L[32 * W1LDW];      //  4608 B

    const int tid  = threadIdx.x;
    const int wave = tid >> 6;
    const int lane = tid & 63;
    const int g    = lane >> 4;
    const int ln   = lane & 15;
    const int base = blockIdx.x * 128;
    const int rows = (B - base < 128) ? (B - base) : 128;
    const int NF4  = T >> 1;   // float4s per x-row (T*2/4)
    const bool g0  = (g == 0);

    // ---- stage x -> XY (coalesced) ----
    {
        const float4* xg = reinterpret_cast<const float4*>(x) + (size_t)base * NF4;
        const int tot = 128 * NF4;
        for (int i = tid; i < tot; i += 256) {
            float4 v = (i < rows * NF4) ? xg[i] : make_float4(0.f, 0.f, 0.f, 0.f);
            int r = i / NF4, c = i - r * NF4;
            *reinterpret_cast<float4*>(&XY[r * XYW + c * 4]) = v;
        }
    }
    // ---- stage KS2 + W1L ----
    {
        const uint32_t* src = reinterpret_cast<const uint32_t*>(wsw + OFF_KS2);
        uint32_t* dst = reinterpret_cast<uint32_t*>(KS2);
        for (int i = tid; i < 1024; i += 256) dst[i] = src[i];
        const uint32_t* s1 = reinterpret_cast<const uint32_t*>(wsw + OFF_W1P);
        uint32_t* d1 = reinterpret_cast<uint32_t*>(W1L);
        for (int i = tid; i < (32 * W1LDW) / 2; i += 256) d1[i] = s1[i];
    }

    // ---- loop-invariant weights -> VGPRs/AGPRs ----
    bf16x8 wR[4][2], wZ[4][2], wN[4][2];
#pragma unroll
    for (int mg = 0; mg < 4; ++mg)
#pragma unroll
        for (int ks = 0; ks < 2; ++ks) {
            wR[mg][ks] = *reinterpret_cast<const bf16x8*>(wsw + ((      mg * 16 + ln) * 64 + ks * 32 + g * 8));
            wZ[mg][ks] = *reinterpret_cast<const bf16x8*>(wsw + ((64  + mg * 16 + ln) * 64 + ks * 32 + g * 8));
            wN[mg][ks] = *reinterpret_cast<const bf16x8*>(wsw + ((128 + mg * 16 + ln) * 64 + ks * 32 + g * 8));
        }
    bf16x8 w2f = *reinterpret_cast<const bf16x8*>(wsw + OFF_W2F + lane * 8);

    f32x4 b1q[2];
#pragma unroll
    for (int mt = 0; mt < 2; ++mt) {
        float4 tv = reinterpret_cast<const float4*>(b1)[mt * 4 + g];
        b1q[mt][0] = tv.x; b1q[mt][1] = tv.y; b1q[mt][2] = tv.z; b1q[mt][3] = tv.w;
    }
    f32x4 dInit;
    {
        float4 bb = *reinterpret_cast<const float4*>(b2);
        dInit[0] = g0 ? bb.x : 0.f;
        dInit[1] = g0 ? bb.y : 0.f;
        dInit[2] = g0 ? bb.z : 0.f;
        dInit[3] = g0 ? bb.w : 0.f;
    }
    const f32x4 Z0 = {0.f, 0.f, 0.f, 0.f};

    // ---- init h (from z, fp32 regs in D-layout), y ----
    float hpr[4][2][4];
    float2 y[2];
    short* hl = &HL[wave][0];
#pragma unroll
    for (int n = 0; n < 2; ++n) {
        int gr = base + wave * 32 + n * 16 + ln;
        bool ok = gr < B;
#pragma unroll
        for (int mg = 0; mg < 4; ++mg) {
            float4 zv = ok ? reinterpret_cast<const float4*>(z)[(size_t)gr * 16 + mg * 4 + g]
                           : make_float4(0.f, 0.f, 0.f, 0.f);
            hpr[mg][n][0] = zv.x; hpr[mg][n][1] = zv.y;
            hpr[mg][n][2] = zv.z; hpr[mg][n][3] = zv.w;
        }
        float2 yv = ok ? reinterpret_cast<const float2*>(y_tm1)[gr] : make_float2(0.f, 0.f);
        y[n] = yv;
    }
    // initial h -> hl (bf16, D-layout store), read initial B-frags
#pragma unroll
    for (int n = 0; n < 2; ++n)
#pragma unroll
        for (int mg = 0; mg < 4; ++mg) {
            uint2 pk;
            pk.x = cvtpk(hpr[mg][n][0], hpr[mg][n][1]);
            pk.y = cvtpk(hpr[mg][n][2], hpr[mg][n][3]);
            *reinterpret_cast<uint2*>(&hl[(n * 16 + ln) * HLW + mg * 16 + g * 4]) = pk;
        }
    bf16x8 hb[2][2];
#pragma unroll
    for (int n = 0; n < 2; ++n)
#pragma unroll
        for (int ks = 0; ks < 2; ++ks)
            hb[n][ks] = *reinterpret_cast<const bf16x8*>(&hl[(n * 16 + ln) * HLW + ks * 32 + g * 8]);

    __syncthreads();

    const uint32_t onepk = g0 ? 0x00003F80u : 0u;   // bf16(1.0) in elem slot 2
    // uniform KS2 base: g>0 lanes read real data but it multiplies zero B-rows
    const volatile bf16x8* k2p = reinterpret_cast<const volatile bf16x8*>(&KS2[ln * 8]);
    const volatile bf16x8* w1p = reinterpret_cast<const volatile bf16x8*>(&W1L[ln * W1LDW + g * 8]);

    for (int t = 0; t < T; ++t) {
        // ks2 B-frags: k=0..2 = [y.x, y.y, 1] on g==0 lanes, else 0
        bf16x8 yb[2];
#pragma unroll
        for (int n = 0; n < 2; ++n) {
            uint32_t ypk = cvtpk(y[n].x, y[n].y);
            union { bf16x8 v; uint32_t u[4]; } yu;
            yu.u[0] = g0 ? ypk : 0u;
            yu.u[1] = onepk;
            yu.u[2] = 0u; yu.u[3] = 0u;
            yb[n] = yu.v;
        }

        // ---- GRU: per (mg, n) to keep live accs at 16 regs ----
#pragma unroll
        for (int mg = 0; mg < 4; ++mg) {
            bf16x8 k2R = k2p[0 * 64 + mg * 16 + 0];   // volatile: stays in-loop
            bf16x8 k2Z = k2p[1 * 64 + mg * 16 + 0];
            bf16x8 k2N = k2p[2 * 64 + mg * 16 + 0];
            bf16x8 k2I = k2p[3 * 64 + mg * 16 + 0];
#pragma unroll
            for (int n = 0; n < 2; ++n) {
                f32x4 aR = __builtin_amdgcn_mfma_f32_16x16x32_bf16(wR[mg][0], hb[n][0], Z0, 0, 0, 0);
                f32x4 aZ = __builtin_amdgcn_mfma_f32_16x16x32_bf16(wZ[mg][0], hb[n][0], Z0, 0, 0, 0);
                f32x4 aN = __builtin_amdgcn_mfma_f32_16x16x32_bf16(wN[mg][0], hb[n][0], Z0, 0, 0, 0);
                f32x4 aI = __builtin_amdgcn_mfma_f32_16x16x32_bf16(k2I,       yb[n],    Z0, 0, 0, 0);
                aR = __builtin_amdgcn_mfma_f32_16x16x32_bf16(wR[mg][1], hb[n][1], aR, 0, 0, 0);
                aZ = __builtin_amdgcn_mfma_f32_16x16x32_bf16(wZ[mg][1], hb[n][1], aZ, 0, 0, 0);
                aN = __builtin_amdgcn_mfma_f32_16x16x32_bf16(wN[mg][1], hb[n][1], aN, 0, 0, 0);
                aR = __builtin_amdgcn_mfma_f32_16x16x32_bf16(k2R, yb[n], aR, 0, 0, 0);
                aZ = __builtin_amdgcn_mfma_f32_16x16x32_bf16(k2Z, yb[n], aZ, 0, 0, 0);
                aN = __builtin_amdgcn_mfma_f32_16x16x32_bf16(k2N, yb[n], aN, 0, 0, 0);

                float hq[4];
#pragma unroll
                for (int q = 0; q < 4; ++q) {
                    float r  = sigf(aR[q]);
                    float u  = sigf(aZ[q]);
                    float nn = tanhf1(fmaf(r, aN[q], aI[q]));
                    float hv = fmaf(u, hpr[mg][n][q] - nn, nn);   // (1-u)*n + u*h
                    hpr[mg][n][q] = hv;
                    hq[q] = hv;
                }
                uint2 pk;
                pk.x = cvtpk(hq[0], hq[1]);
                pk.y = cvtpk(hq[2], hq[3]);
                *reinterpret_cast<uint2*>(&hl[(n * 16 + ln) * HLW + mg * 16 + g * 4]) = pk;
            }
        }

        // ---- re-read h' B-frags (used by MLP1 now and GRU next step) ----
#pragma unroll
        for (int n = 0; n < 2; ++n)
#pragma unroll
            for (int ks = 0; ks < 2; ++ks)
                hb[n][ks] = *reinterpret_cast<const bf16x8*>(&hl[(n * 16 + ln) * HLW + ks * 32 + g * 8]);

        // ---- MLP1 via MFMA (b1 as C-operand) ----
        f32x4 aM[2][2];
#pragma unroll
        for (int mt = 0; mt < 2; ++mt) {
            bf16x8 wM0 = w1p[mt * 16 * (W1LDW / 8) + 0];
            bf16x8 wM1 = w1p[mt * 16 * (W1LDW / 8) + 4];   // +32 shorts = 4 bf16x8
#pragma unroll
            for (int n = 0; n < 2; ++n) {
                f32x4 a = __builtin_amdgcn_mfma_f32_16x16x32_bf16(wM0, hb[n][0], b1q[mt], 0, 0, 0);
                aM[mt][n] = __builtin_amdgcn_mfma_f32_16x16x32_bf16(wM1, hb[n][1], a, 0, 0, 0);
            }
        }

        // ---- relu(a) -> hl cols 64..95, MLP2 via padded MFMA ----
#pragma unroll
        for (int n = 0; n < 2; ++n)
#pragma unroll
            for (int mt = 0; mt < 2; ++mt) {
                uint2 pk;
                pk.x = cvtpk(fmaxf(aM[mt][n][0], 0.f), fmaxf(aM[mt][n][1], 0.f));
                pk.y = cvtpk(fmaxf(aM[mt][n][2], 0.f), fmaxf(aM[mt][n][3], 0.f));
                *reinterpret_cast<uint2*>(&hl[(n * 16 + ln) * HLW + 64 + mt * 16 + g * 4]) = pk;
            }
        f32x4 aD[2];
#pragma unroll
        for (int n = 0; n < 2; ++n) {
            bf16x8 ab = *reinterpret_cast<const bf16x8*>(&hl[(n * 16 + ln) * HLW + 64 + g * 8]);
            aD[n] = __builtin_amdgcn_mfma_f32_16x16x32_bf16(w2f, ab, dInit, 0, 0, 0);
        }

        // ---- flow update (d valid on g==0 lanes; aD==0 on g>0 so y stays finite) ----
#pragma unroll
        for (int n = 0; n < 2; ++n) {
            int rl = wave * 32 + n * 16 + ln;
            float2 xt = *reinterpret_cast<const float2*>(&XY[rl * XYW + t * 2]);
            float s0 = softplusf(aD[n][2]) + 1e-6f;
            float s1 = softplusf(aD[n][3]) + 1e-6f;
            y[n].x += aD[n][0] + s0 * xt.x;
            y[n].y += aD[n][1] + s1 * xt.y;
            if (g0)
                *reinterpret_cast<float2*>(&XY[rl * XYW + t * 2]) = y[n];
        }
    }

    __syncthreads();
    // ---- coalesced store XY -> out ----
    {
        float4* og = reinterpret_cast<float4*>(out) + (size_t)base * NF4;
        const int tot = 128 * NF4;
        for (int i = tid; i < tot; i += 256) {
            if (i < rows * NF4) {
                int r = i / NF4, c = i - r * NF4;
                og[i] = *reinterpret_cast<const float4*>(&XY[r * XYW + c * 4]);
            }
        }
    }
}

extern "C" void kernel_launch(void* const* d_in, const int* in_sizes, int n_in,
                              void* d_out, int out_size, void* d_ws, size_t ws_size,
                              hipStream_t stream) {
    const float* y_tm1 = (const float*)d_in[0];
    const float* z     = (const float*)d_in[1];
    const float* x     = (const float*)d_in[2];
    const float* Wih   = (const float*)d_in[3];
    const float* Whh   = (const float*)d_in[4];
    const float* bih   = (const float*)d_in[5];
    const float* bhh   = (const float*)d_in[6];
    const float* W1    = (const float*)d_in[7];
    const float* b1    = (const float*)d_in[8];
    const float* W2    = (const float*)d_in[9];
    const float* b2    = (const float*)d_in[10];
    float* out = (float*)d_out;
    short* wsw = (short*)d_ws;

    const int B = in_sizes[0] / 2;
    const int T = in_sizes[2] / in_sizes[0];

    hipLaunchKernelGGL(prep_kernel, dim3((WS_TOT + 255) / 256), dim3(256), 0, stream,
                       Wih, Whh, bih, bhh, W1, W2, wsw);

    const int nblk = (B + 127) / 128;
    hipLaunchKernelGGL(arflow4, dim3(nblk), dim3(256), 0, stream,
                       y_tm1, z, x, b1, b2, wsw, out, B, T);
}